// Round 1
// baseline (157.429 us; speedup 1.0000x reference)
//
#include <hip/hip_runtime.h>
#include <hip/hip_bf16.h>

#define NROW 4096
#define KDIM 2048
#define BM 128
#define BN 128
#define BK 32

typedef __attribute__((ext_vector_type(8))) short bf16x8;
typedef __attribute__((ext_vector_type(4))) float f32x4;
typedef __attribute__((ext_vector_type(4))) unsigned short u16x4;

__device__ __forceinline__ unsigned short f2bf(float x) {
    unsigned u = __float_as_uint(x);
    unsigned r = (u + 0x7FFFu + ((u >> 16) & 1u)) >> 16;
    return (unsigned short)r;
}
__device__ __forceinline__ float bf2f(unsigned short b) {
    return __uint_as_float(((unsigned)b) << 16);
}

// Kernel 1: fp32 -> bf16 copy + row sum-of-squares (computed FROM the bf16
// values so the Gram diagonal stays ~0, consistent with the MFMA dot).
__global__ __launch_bounds__(256) void k_convert(const float* __restrict__ X,
                                                 unsigned short* __restrict__ Xb,
                                                 float* __restrict__ sqv) {
    const int row = blockIdx.x;
    const int t = threadIdx.x;
    const float4* xr = (const float4*)(X + (size_t)row * KDIM);
    unsigned short* br = Xb + (size_t)row * KDIM;
    float acc = 0.f;
#pragma unroll
    for (int it = 0; it < 2; ++it) {
        int idx = t * 2 + it;  // float4 index 0..511
        float4 v = xr[idx];
        u16x4 b;
        b.x = f2bf(v.x); b.y = f2bf(v.y); b.z = f2bf(v.z); b.w = f2bf(v.w);
        float f0 = bf2f(b.x), f1 = bf2f(b.y), f2 = bf2f(b.z), f3 = bf2f(b.w);
        acc += f0 * f0 + f1 * f1 + f2 * f2 + f3 * f3;
        *(u16x4*)(br + idx * 4) = b;
    }
#pragma unroll
    for (int s = 32; s > 0; s >>= 1) acc += __shfl_xor(acc, s);
    __shared__ float red[4];
    const int lane = t & 63, wid = t >> 6;
    if (lane == 0) red[wid] = acc;
    __syncthreads();
    if (t == 0) sqv[row] = red[0] + red[1] + red[2] + red[3];
}

// Kernel 2: init per-row accumulators. All candidate dists are >= 1e-6 > 0,
// so uint-bit atomicMax/Min ordering is valid; max-init = 0.0f bits,
// min-init = +inf bits.
__global__ __launch_bounds__(256) void k_init(unsigned* hp, unsigned* hn,
                                              unsigned* mor, unsigned* mir,
                                              int* anyor) {
    int i = blockIdx.x * 256 + threadIdx.x;
    hp[i] = 0u;
    hn[i] = 0x7F800000u;
    mor[i] = 0u;
    mir[i] = 0x7F800000u;
    anyor[i] = 0;
}

// Kernel 3: fused Gram-GEMM (bf16 MFMA, m97 structure) + per-row masked
// max/min reductions via 16-lane shuffles + global atomics.
__global__ __launch_bounds__(256) void k_gemm(const unsigned short* __restrict__ Xb,
                                              const float* __restrict__ sqv,
                                              const int* __restrict__ ta,
                                              const int* __restrict__ tb,
                                              unsigned int* __restrict__ hp,
                                              unsigned int* __restrict__ hn,
                                              unsigned int* __restrict__ mor,
                                              unsigned int* __restrict__ mir,
                                              int* __restrict__ anyor) {
    __shared__ unsigned short lds_a[BM * BK];
    __shared__ unsigned short lds_b[BN * BK];
    const int bi = blockIdx.x / (NROW / BN);
    const int bj = blockIdx.x % (NROW / BN);
    const int t = threadIdx.x;
    const int lane = t & 63;
    const int wid = t >> 6;
    const int wm = wid >> 1, wn = wid & 1;

    f32x4 acc[4][4] = {};

    // staging: chunk ch (16B) at lds byte ch*16; ch = t and t+256.
    // ch -> row = ch>>2, col8 = (ch&3)*8
    const unsigned short* ga = Xb + (size_t)(bi * BM + (t >> 2)) * KDIM + (t & 3) * 8;
    const unsigned short* gb = Xb + (size_t)(bj * BN + (t >> 2)) * KDIM + (t & 3) * 8;
    unsigned short* la = lds_a + t * 8;
    unsigned short* lb = lds_b + t * 8;

    const int r0 = wm * 64 + (lane & 15);
    const int c0 = wn * 64 + (lane & 15);
    const int k0 = (lane >> 4) * 8;

    for (int kt = 0; kt < KDIM / BK; ++kt) {
        const int ko = kt * BK;
        __syncthreads();  // previous tile fully consumed
        __builtin_amdgcn_global_load_lds(
            (const __attribute__((address_space(1))) void*)(ga + ko),
            (__attribute__((address_space(3))) void*)la, 16, 0, 0);
        __builtin_amdgcn_global_load_lds(
            (const __attribute__((address_space(1))) void*)(ga + (size_t)64 * KDIM + ko),
            (__attribute__((address_space(3))) void*)(la + 2048), 16, 0, 0);
        __builtin_amdgcn_global_load_lds(
            (const __attribute__((address_space(1))) void*)(gb + ko),
            (__attribute__((address_space(3))) void*)lb, 16, 0, 0);
        __builtin_amdgcn_global_load_lds(
            (const __attribute__((address_space(1))) void*)(gb + (size_t)64 * KDIM + ko),
            (__attribute__((address_space(3))) void*)(lb + 2048), 16, 0, 0);
        __syncthreads();  // vmcnt(0) drain + barrier -> LDS valid

        bf16x8 af[4], bfr[4];
#pragma unroll
        for (int m = 0; m < 4; ++m)
            af[m] = *(const bf16x8*)(lds_a + (r0 + m * 16) * BK + k0);
#pragma unroll
        for (int n = 0; n < 4; ++n)
            bfr[n] = *(const bf16x8*)(lds_b + (c0 + n * 16) * BK + k0);
#pragma unroll
        for (int m = 0; m < 4; ++m)
#pragma unroll
            for (int n = 0; n < 4; ++n)
                acc[m][n] = __builtin_amdgcn_mfma_f32_16x16x32_bf16(af[m], bfr[n],
                                                                    acc[m][n], 0, 0, 0);
    }

    // ---- epilogue: dist + masks + row reductions ----
    float sqj[4];
    int taj[4], tbj[4];
#pragma unroll
    for (int n = 0; n < 4; ++n) {
        int j = bj * BN + c0 + n * 16;
        sqj[n] = sqv[j];
        taj[n] = ta[j];
        tbj[n] = tb[j];
    }
    const float INF = __uint_as_float(0x7F800000u);
#pragma unroll
    for (int m = 0; m < 4; ++m) {
#pragma unroll
        for (int reg = 0; reg < 4; ++reg) {
            const int i = bi * BM + wm * 64 + m * 16 + (lane >> 4) * 4 + reg;
            const float sqi = sqv[i];
            const int tai = ta[i], tbi = tb[i];
            float vhp = 0.f, vhn = INF, vmor = 0.f, vmir = INF, vany = 0.f;
#pragma unroll
            for (int n = 0; n < 4; ++n) {
                float d2 = sqi + sqj[n] - 2.f * acc[m][n][reg];
                float d = sqrtf(fmaxf(d2, 1e-12f));
                bool ma = (tai == taj[n]), mb = (tbi == tbj[n]);
                if (ma && mb) {
                    vhp = fmaxf(vhp, d);
                } else if (ma != mb) {
                    vmor = fmaxf(vmor, d);
                    vmir = fminf(vmir, d);
                    vany = 1.f;
                } else {
                    vhn = fminf(vhn, d);
                }
            }
#pragma unroll
            for (int s = 1; s < 16; s <<= 1) {
                vhp = fmaxf(vhp, __shfl_xor(vhp, s, 16));
                vhn = fminf(vhn, __shfl_xor(vhn, s, 16));
                vmor = fmaxf(vmor, __shfl_xor(vmor, s, 16));
                vmir = fminf(vmir, __shfl_xor(vmir, s, 16));
                vany = fmaxf(vany, __shfl_xor(vany, s, 16));
            }
            if ((lane & 15) == 0) {
                if (vhp > 0.f) atomicMax(&hp[i], __float_as_uint(vhp));
                if (vhn < INF) atomicMin(&hn[i], __float_as_uint(vhn));
                if (vany > 0.f) {
                    atomicMax(&mor[i], __float_as_uint(vmor));
                    atomicMin(&mir[i], __float_as_uint(vmir));
                    atomicOr(&anyor[i], 1);
                }
            }
        }
    }
}

// Kernel 4: final scalar loss.
__global__ __launch_bounds__(256) void k_final(const unsigned* __restrict__ hp,
                                               const unsigned* __restrict__ hn,
                                               const unsigned* __restrict__ mor,
                                               const unsigned* __restrict__ mir,
                                               const int* __restrict__ anyor,
                                               const int* __restrict__ epoch_p,
                                               float* __restrict__ out) {
    const int t = threadIdx.x;
    const bool eok = (*epoch_p > 50);
    float s = 0.f;
    for (int i = t; i < NROW; i += 256) {
        float fhp = __uint_as_float(hp[i]);
        float fhn = __uint_as_float(hn[i]);
        bool use_or = (anyor[i] != 0) && eok;
        float sp = use_or ? __uint_as_float(mor[i]) : fhp;
        float sn = use_or ? __uint_as_float(mir[i]) : fhn;
        s += fmaxf(0.f, fhp - fhn + 0.3f);
        s += fmaxf(0.f, sp - fhn + 0.3f);
        s += fmaxf(0.f, fhp - sn + 0.3f);
    }
#pragma unroll
    for (int sh = 32; sh > 0; sh >>= 1) s += __shfl_xor(s, sh);
    __shared__ float red[4];
    const int lane = t & 63, wid = t >> 6;
    if (lane == 0) red[wid] = s;
    __syncthreads();
    if (t == 0) out[0] = (red[0] + red[1] + red[2] + red[3]) * (1.f / 4096.f);
}

extern "C" void kernel_launch(void* const* d_in, const int* in_sizes, int n_in,
                              void* d_out, int out_size, void* d_ws, size_t ws_size,
                              hipStream_t stream) {
    const float* X = (const float*)d_in[0];
    const int* ta = (const int*)d_in[1];
    const int* tb = (const int*)d_in[2];
    const int* epoch_p = (const int*)d_in[4];
    float* out = (float*)d_out;

    char* ws = (char*)d_ws;
    unsigned short* Xb = (unsigned short*)ws;  // 16 MB bf16 copy
    size_t off = (size_t)NROW * KDIM * sizeof(unsigned short);
    float* sqv = (float*)(ws + off); off += (size_t)NROW * 4;
    unsigned* hp = (unsigned*)(ws + off); off += (size_t)NROW * 4;
    unsigned* hn = (unsigned*)(ws + off); off += (size_t)NROW * 4;
    unsigned* mor = (unsigned*)(ws + off); off += (size_t)NROW * 4;
    unsigned* mir = (unsigned*)(ws + off); off += (size_t)NROW * 4;
    int* anyor = (int*)(ws + off); off += (size_t)NROW * 4;

    k_convert<<<NROW, 256, 0, stream>>>(X, Xb, sqv);
    k_init<<<NROW / 256, 256, 0, stream>>>(hp, hn, mor, mir, anyor);
    k_gemm<<<(NROW / BM) * (NROW / BN), 256, 0, stream>>>(Xb, sqv, ta, tb,
                                                          hp, hn, mor, mir, anyor);
    k_final<<<1, 256, 0, stream>>>(hp, hn, mor, mir, anyor, epoch_p, out);
}

// Round 2
// 145.560 us; speedup vs baseline: 1.0815x; 1.0815x over previous
//
#include <hip/hip_runtime.h>
#include <hip/hip_bf16.h>

#define NROW 4096
#define KDIM 2048
#define BM 128
#define BN 128
#define BK 32
#define NB (NROW / BM)  // 32 block-rows; upper-triangle grid = NB*(NB+1)/2 = 528

typedef __attribute__((ext_vector_type(8))) short bf16x8;
typedef __attribute__((ext_vector_type(4))) float f32x4;
typedef __attribute__((ext_vector_type(4))) unsigned short u16x4;

__device__ __forceinline__ unsigned short f2bf(float x) {
    unsigned u = __float_as_uint(x);
    unsigned r = (u + 0x7FFFu + ((u >> 16) & 1u)) >> 16;
    return (unsigned short)r;
}
__device__ __forceinline__ float bf2f(unsigned short b) {
    return __uint_as_float(((unsigned)b) << 16);
}

// Kernel 1: fp32 -> bf16 copy + row sum-of-squares (computed FROM the bf16
// values so the Gram diagonal stays ~0, consistent with the MFMA dot).
__global__ __launch_bounds__(256) void k_convert(const float* __restrict__ X,
                                                 unsigned short* __restrict__ Xb,
                                                 float* __restrict__ sqv) {
    const int row = blockIdx.x;
    const int t = threadIdx.x;
    const float4* xr = (const float4*)(X + (size_t)row * KDIM);
    unsigned short* br = Xb + (size_t)row * KDIM;
    float acc = 0.f;
#pragma unroll
    for (int it = 0; it < 2; ++it) {
        int idx = t * 2 + it;  // float4 index 0..511
        float4 v = xr[idx];
        u16x4 b;
        b.x = f2bf(v.x); b.y = f2bf(v.y); b.z = f2bf(v.z); b.w = f2bf(v.w);
        float f0 = bf2f(b.x), f1 = bf2f(b.y), f2 = bf2f(b.z), f3 = bf2f(b.w);
        acc += f0 * f0 + f1 * f1 + f2 * f2 + f3 * f3;
        *(u16x4*)(br + idx * 4) = b;
    }
#pragma unroll
    for (int s = 32; s > 0; s >>= 1) acc += __shfl_xor(acc, s);
    __shared__ float red[4];
    const int lane = t & 63, wid = t >> 6;
    if (lane == 0) red[wid] = acc;
    __syncthreads();
    if (t == 0) sqv[row] = red[0] + red[1] + red[2] + red[3];
}

// Kernel 2: init per-row accumulators. All candidate dists are >= 1e-6 > 0,
// so uint-bit atomicMax/Min ordering is valid; max-init = 0.0f bits,
// min-init = +inf bits.
__global__ __launch_bounds__(256) void k_init(unsigned* hp, unsigned* hn,
                                              unsigned* mor, unsigned* mir,
                                              int* anyor) {
    int i = blockIdx.x * 256 + threadIdx.x;
    hp[i] = 0u;
    hn[i] = 0x7F800000u;
    mor[i] = 0u;
    mir[i] = 0x7F800000u;
    anyor[i] = 0;
}

// Kernel 3: fused Gram-GEMM (bf16 MFMA, m97 structure), UPPER-TRIANGLE ONLY.
// dist and both masks are symmetric; all reductions are max/min/or
// (idempotent), so off-diagonal blocks contribute to BOTH row i (row-side
// shuffle reduce) and row j (column-side reduce over m/reg + lane-group
// shuffles). Diagonal blocks do row-side only.
__global__ __launch_bounds__(256) void k_gemm(const unsigned short* __restrict__ Xb,
                                              const float* __restrict__ sqv,
                                              const int* __restrict__ ta,
                                              const int* __restrict__ tb,
                                              unsigned int* __restrict__ hp,
                                              unsigned int* __restrict__ hn,
                                              unsigned int* __restrict__ mor,
                                              unsigned int* __restrict__ mir,
                                              int* __restrict__ anyor) {
    __shared__ unsigned short lds_a[BM * BK];
    __shared__ unsigned short lds_b[BN * BK];
    // triangle decode: block-row bi has (NB - bi) blocks, bj in [bi, NB)
    int rem = blockIdx.x;
    int bi = 0;
    while (rem >= NB - bi) { rem -= NB - bi; ++bi; }
    const int bj = bi + rem;

    const int t = threadIdx.x;
    const int lane = t & 63;
    const int wid = t >> 6;
    const int wm = wid >> 1, wn = wid & 1;

    f32x4 acc[4][4] = {};

    const unsigned short* ga = Xb + (size_t)(bi * BM + (t >> 2)) * KDIM + (t & 3) * 8;
    const unsigned short* gb = Xb + (size_t)(bj * BN + (t >> 2)) * KDIM + (t & 3) * 8;
    unsigned short* la = lds_a + t * 8;
    unsigned short* lb = lds_b + t * 8;

    const int r0 = wm * 64 + (lane & 15);
    const int c0 = wn * 64 + (lane & 15);
    const int k0 = (lane >> 4) * 8;

    for (int kt = 0; kt < KDIM / BK; ++kt) {
        const int ko = kt * BK;
        __syncthreads();  // previous tile fully consumed
        __builtin_amdgcn_global_load_lds(
            (const __attribute__((address_space(1))) void*)(ga + ko),
            (__attribute__((address_space(3))) void*)la, 16, 0, 0);
        __builtin_amdgcn_global_load_lds(
            (const __attribute__((address_space(1))) void*)(ga + (size_t)64 * KDIM + ko),
            (__attribute__((address_space(3))) void*)(la + 2048), 16, 0, 0);
        __builtin_amdgcn_global_load_lds(
            (const __attribute__((address_space(1))) void*)(gb + ko),
            (__attribute__((address_space(3))) void*)lb, 16, 0, 0);
        __builtin_amdgcn_global_load_lds(
            (const __attribute__((address_space(1))) void*)(gb + (size_t)64 * KDIM + ko),
            (__attribute__((address_space(3))) void*)(lb + 2048), 16, 0, 0);
        __syncthreads();  // vmcnt(0) drain + barrier -> LDS valid

        bf16x8 af[4], bfr[4];
#pragma unroll
        for (int m = 0; m < 4; ++m)
            af[m] = *(const bf16x8*)(lds_a + (r0 + m * 16) * BK + k0);
#pragma unroll
        for (int n = 0; n < 4; ++n)
            bfr[n] = *(const bf16x8*)(lds_b + (c0 + n * 16) * BK + k0);
#pragma unroll
        for (int m = 0; m < 4; ++m)
#pragma unroll
            for (int n = 0; n < 4; ++n)
                acc[m][n] = __builtin_amdgcn_mfma_f32_16x16x32_bf16(af[m], bfr[n],
                                                                    acc[m][n], 0, 0, 0);
    }

    // ---- epilogue: dist + masks + row/col reductions ----
    float sqj[4];
    int taj[4], tbj[4];
#pragma unroll
    for (int n = 0; n < 4; ++n) {
        int j = bj * BN + c0 + n * 16;
        sqj[n] = sqv[j];
        taj[n] = ta[j];
        tbj[n] = tb[j];
    }
    const float INF = __uint_as_float(0x7F800000u);

    // column-side accumulators (per n, reduced over m/reg in-thread)
    float chp[4], chn[4], cmor[4], cmir[4], cany[4];
#pragma unroll
    for (int n = 0; n < 4; ++n) {
        chp[n] = 0.f; chn[n] = INF; cmor[n] = 0.f; cmir[n] = INF; cany[n] = 0.f;
    }

#pragma unroll
    for (int m = 0; m < 4; ++m) {
#pragma unroll
        for (int reg = 0; reg < 4; ++reg) {
            const int i = bi * BM + wm * 64 + m * 16 + (lane >> 4) * 4 + reg;
            const float sqi = sqv[i];
            const int tai = ta[i], tbi = tb[i];
            float vhp = 0.f, vhn = INF, vmor = 0.f, vmir = INF, vany = 0.f;
#pragma unroll
            for (int n = 0; n < 4; ++n) {
                float d2 = sqi + sqj[n] - 2.f * acc[m][n][reg];
                float d = sqrtf(fmaxf(d2, 1e-12f));
                bool ma = (tai == taj[n]), mb = (tbi == tbj[n]);
                if (ma && mb) {
                    vhp = fmaxf(vhp, d);
                    chp[n] = fmaxf(chp[n], d);
                } else if (ma != mb) {
                    vmor = fmaxf(vmor, d);
                    vmir = fminf(vmir, d);
                    vany = 1.f;
                    cmor[n] = fmaxf(cmor[n], d);
                    cmir[n] = fminf(cmir[n], d);
                    cany[n] = 1.f;
                } else {
                    vhn = fminf(vhn, d);
                    chn[n] = fminf(chn[n], d);
                }
            }
#pragma unroll
            for (int s = 1; s < 16; s <<= 1) {
                vhp = fmaxf(vhp, __shfl_xor(vhp, s, 16));
                vhn = fminf(vhn, __shfl_xor(vhn, s, 16));
                vmor = fmaxf(vmor, __shfl_xor(vmor, s, 16));
                vmir = fminf(vmir, __shfl_xor(vmir, s, 16));
                vany = fmaxf(vany, __shfl_xor(vany, s, 16));
            }
            if ((lane & 15) == 0) {
                if (vhp > 0.f) atomicMax(&hp[i], __float_as_uint(vhp));
                if (vhn < INF) atomicMin(&hn[i], __float_as_uint(vhn));
                if (vany > 0.f) {
                    atomicMax(&mor[i], __float_as_uint(vmor));
                    atomicMin(&mir[i], __float_as_uint(vmir));
                    atomicOr(&anyor[i], 1);
                }
            }
        }
    }

    if (bi != bj) {
        // column-side: reduce across the 4 row-groups (lane>>4) via xor-16/32
#pragma unroll
        for (int n = 0; n < 4; ++n) {
            float a = chp[n], b = chn[n], c = cmor[n], d = cmir[n], e = cany[n];
            a = fmaxf(a, __shfl_xor(a, 16)); a = fmaxf(a, __shfl_xor(a, 32));
            b = fminf(b, __shfl_xor(b, 16)); b = fminf(b, __shfl_xor(b, 32));
            c = fmaxf(c, __shfl_xor(c, 16)); c = fmaxf(c, __shfl_xor(c, 32));
            d = fminf(d, __shfl_xor(d, 16)); d = fminf(d, __shfl_xor(d, 32));
            e = fmaxf(e, __shfl_xor(e, 16)); e = fmaxf(e, __shfl_xor(e, 32));
            if (lane < 16) {
                const int j = bj * BN + wn * 64 + n * 16 + lane;
                if (a > 0.f) atomicMax(&hp[j], __float_as_uint(a));
                if (b < INF) atomicMin(&hn[j], __float_as_uint(b));
                if (e > 0.f) {
                    atomicMax(&mor[j], __float_as_uint(c));
                    atomicMin(&mir[j], __float_as_uint(d));
                    atomicOr(&anyor[j], 1);
                }
            }
        }
    }
}

// Kernel 4: final scalar loss.
__global__ __launch_bounds__(256) void k_final(const unsigned* __restrict__ hp,
                                               const unsigned* __restrict__ hn,
                                               const unsigned* __restrict__ mor,
                                               const unsigned* __restrict__ mir,
                                               const int* __restrict__ anyor,
                                               const int* __restrict__ epoch_p,
                                               float* __restrict__ out) {
    const int t = threadIdx.x;
    const bool eok = (*epoch_p > 50);
    float s = 0.f;
    for (int i = t; i < NROW; i += 256) {
        float fhp = __uint_as_float(hp[i]);
        float fhn = __uint_as_float(hn[i]);
        bool use_or = (anyor[i] != 0) && eok;
        float sp = use_or ? __uint_as_float(mor[i]) : fhp;
        float sn = use_or ? __uint_as_float(mir[i]) : fhn;
        s += fmaxf(0.f, fhp - fhn + 0.3f);
        s += fmaxf(0.f, sp - fhn + 0.3f);
        s += fmaxf(0.f, fhp - sn + 0.3f);
    }
#pragma unroll
    for (int sh = 32; sh > 0; sh >>= 1) s += __shfl_xor(s, sh);
    __shared__ float red[4];
    const int lane = t & 63, wid = t >> 6;
    if (lane == 0) red[wid] = s;
    __syncthreads();
    if (t == 0) out[0] = (red[0] + red[1] + red[2] + red[3]) * (1.f / 4096.f);
}

extern "C" void kernel_launch(void* const* d_in, const int* in_sizes, int n_in,
                              void* d_out, int out_size, void* d_ws, size_t ws_size,
                              hipStream_t stream) {
    const float* X = (const float*)d_in[0];
    const int* ta = (const int*)d_in[1];
    const int* tb = (const int*)d_in[2];
    const int* epoch_p = (const int*)d_in[4];
    float* out = (float*)d_out;

    char* ws = (char*)d_ws;
    unsigned short* Xb = (unsigned short*)ws;  // 16 MB bf16 copy
    size_t off = (size_t)NROW * KDIM * sizeof(unsigned short);
    float* sqv = (float*)(ws + off); off += (size_t)NROW * 4;
    unsigned* hp = (unsigned*)(ws + off); off += (size_t)NROW * 4;
    unsigned* hn = (unsigned*)(ws + off); off += (size_t)NROW * 4;
    unsigned* mor = (unsigned*)(ws + off); off += (size_t)NROW * 4;
    unsigned* mir = (unsigned*)(ws + off); off += (size_t)NROW * 4;
    int* anyor = (int*)(ws + off); off += (size_t)NROW * 4;

    k_convert<<<NROW, 256, 0, stream>>>(X, Xb, sqv);
    k_init<<<NROW / 256, 256, 0, stream>>>(hp, hn, mor, mir, anyor);
    k_gemm<<<(NB * (NB + 1)) / 2, 256, 0, stream>>>(Xb, sqv, ta, tb,
                                                    hp, hn, mor, mir, anyor);
    k_final<<<1, 256, 0, stream>>>(hp, hn, mor, mir, anyor, epoch_p, out);
}

// Round 3
// 112.665 us; speedup vs baseline: 1.3973x; 1.2920x over previous
//
#include <hip/hip_runtime.h>
#include <hip/hip_bf16.h>

#define NROW 4096
#define KDIM 2048
#define ROWB (KDIM * 2)     // bytes per Xb row
#define BT 256              // block tile (M = N)
#define BK 32               // k-tile depth (64 bytes)
#define NT (KDIM / BK)      // 64 k-tiles
#define LDSBUF 32768        // per k-tile: A 16 KB + B 16 KB
#define PHI(r) ((((r) >> 1) & 3) << 4)

typedef __attribute__((ext_vector_type(8))) short bf16x8;
typedef __attribute__((ext_vector_type(4))) float f32x4;
typedef __attribute__((ext_vector_type(4))) unsigned short u16x4;

__device__ __forceinline__ unsigned short f2bf(float x) {
    unsigned u = __float_as_uint(x);
    unsigned r = (u + 0x7FFFu + ((u >> 16) & 1u)) >> 16;
    return (unsigned short)r;
}
__device__ __forceinline__ float bf2f(unsigned short b) {
    return __uint_as_float(((unsigned)b) << 16);
}

// Kernel 1: fp32 -> bf16 copy + row sum-of-squares from the bf16 values.
__global__ __launch_bounds__(256) void k_convert(const float* __restrict__ X,
                                                 unsigned short* __restrict__ Xb,
                                                 float* __restrict__ sqv) {
    const int row = blockIdx.x;
    const int t = threadIdx.x;
    const float4* xr = (const float4*)(X + (size_t)row * KDIM);
    unsigned short* br = Xb + (size_t)row * KDIM;
    float acc = 0.f;
#pragma unroll
    for (int it = 0; it < 2; ++it) {
        int idx = t * 2 + it;
        float4 v = xr[idx];
        u16x4 b;
        b.x = f2bf(v.x); b.y = f2bf(v.y); b.z = f2bf(v.z); b.w = f2bf(v.w);
        float f0 = bf2f(b.x), f1 = bf2f(b.y), f2 = bf2f(b.z), f3 = bf2f(b.w);
        acc += f0 * f0 + f1 * f1 + f2 * f2 + f3 * f3;
        *(u16x4*)(br + idx * 4) = b;
    }
#pragma unroll
    for (int s = 32; s > 0; s >>= 1) acc += __shfl_xor(acc, s);
    __shared__ float red[4];
    const int lane = t & 63, wid = t >> 6;
    if (lane == 0) red[wid] = acc;
    __syncthreads();
    if (t == 0) sqv[row] = red[0] + red[1] + red[2] + red[3];
}

// Kernel 2: init per-row accumulators + zero the output scalar.
__global__ __launch_bounds__(256) void k_init(unsigned* hp, unsigned* hn,
                                              unsigned* mor, unsigned* mir,
                                              int* anyor, float* out) {
    int i = blockIdx.x * 256 + threadIdx.x;
    hp[i] = 0u;
    hn[i] = 0x7F800000u;
    mor[i] = 0u;
    mir[i] = 0x7F800000u;
    anyor[i] = 0;
    if (i == 0) out[0] = 0.f;
}

// Kernel 3: 256x256-tile Gram GEMM, 8 waves, BK=32, 3-deep LDS pipeline with
// counted vmcnt (T3+T4), setprio around MFMA clusters (T5), XOR-swizzled LDS
// via pre-swizzled global source (T2 / rule #21). Row-side epilogue.
__global__ __launch_bounds__(512, 2) void k_gemm(const unsigned short* __restrict__ Xb,
                                                 const float* __restrict__ sqv,
                                                 const int* __restrict__ ta,
                                                 const int* __restrict__ tb,
                                                 unsigned int* __restrict__ hp,
                                                 unsigned int* __restrict__ hn,
                                                 unsigned int* __restrict__ mor,
                                                 unsigned int* __restrict__ mir,
                                                 int* __restrict__ anyor) {
    __shared__ char lds[3 * LDSBUF];  // 96 KiB: 3 x (A 16K + B 16K)
    const int bi = blockIdx.x >> 4;
    const int bj = blockIdx.x & 15;
    const int t = threadIdx.x;
    const int lane = t & 63;
    const int w = t >> 6;        // wave 0..7
    const int wm = w >> 2;       // 0..1  (128-row half)
    const int wn = w & 3;        // 0..3  (64-col quarter)
    const int l15 = lane & 15;
    const int k16 = (lane >> 4) * 16;  // byte offset of k-slot within 64B row

    // staging geometry: wave w stages rows w*16..w*16+15 of each 128-row half
    const int srow = w * 16 + (lane >> 2);   // 0..127 within half
    const int scol = (lane & 3) * 16;        // 16B block within 64B row
    const char* xbase = (const char*)Xb;

    // swizzled ds_read offsets (within a buffer)
    int aoffs[8], boffs[4];
#pragma unroll
    for (int m = 0; m < 8; ++m) {
        int r = wm * 128 + m * 16 + l15;
        aoffs[m] = r * 64 + (k16 ^ PHI(r));
    }
#pragma unroll
    for (int n = 0; n < 4; ++n) {
        int j = wn * 64 + n * 16 + l15;
        boffs[n] = 16384 + j * 64 + (k16 ^ PHI(j));
    }

    f32x4 acc[8][4] = {};

    // stage quarter p of k-tile tt into buf tt%3. Linear LDS dest
    // (wave base + lane*16); swizzle applied on the GLOBAL source address.
#define STAGE(tt, p)                                                          \
    do {                                                                      \
        const int isb_ = (p) >> 1, half_ = (p) & 1;                           \
        const int R_ = half_ * 128 + srow;                                    \
        const int gr_ = (isb_ ? bj : bi) * BT + R_;                           \
        const char* gsrc_ = xbase + (size_t)gr_ * ROWB + (size_t)(tt) * 64 +  \
                            (scol ^ PHI(R_));                                 \
        char* ldst_ = lds + ((tt) % 3) * LDSBUF + isb_ * 16384 + R_ * 64 + scol; \
        __builtin_amdgcn_global_load_lds(                                     \
            (const __attribute__((address_space(1))) void*)gsrc_,             \
            (__attribute__((address_space(3))) void*)ldst_, 16, 0, 0);        \
    } while (0)

    // prologue: stage tiles 0 and 1 (8 loads/wave outstanding)
#pragma unroll
    for (int p = 0; p < 4; ++p) STAGE(0, p);
#pragma unroll
    for (int p = 0; p < 4; ++p) STAGE(1, p);

    bf16x8 af[4], bfr[4];
    for (int tk = 0; tk < NT; ++tk) {
        // tile tk complete when all but the newest 4 loads (tile tk+1) land
        if (tk < NT - 1)
            asm volatile("s_waitcnt vmcnt(4)" ::: "memory");
        else
            asm volatile("s_waitcnt vmcnt(0)" ::: "memory");
        __builtin_amdgcn_s_barrier();
        __builtin_amdgcn_sched_barrier(0);
        const char* Ab = lds + (tk % 3) * LDSBUF;
        const bool st = (tk + 2) < NT;
        const int t2 = tk + 2;

        // ---- phase 0: load A m0-3 + B n0-1, compute quadrant (m0-3, n0-1)
        if (st) STAGE(t2, 0);
#pragma unroll
        for (int m = 0; m < 4; ++m) af[m] = *(const bf16x8*)(Ab + aoffs[m]);
        bfr[0] = *(const bf16x8*)(Ab + boffs[0]);
        bfr[1] = *(const bf16x8*)(Ab + boffs[1]);
        __builtin_amdgcn_s_barrier();
        __builtin_amdgcn_s_setprio(1);
#pragma unroll
        for (int m = 0; m < 4; ++m) {
            acc[m][0] = __builtin_amdgcn_mfma_f32_16x16x32_bf16(af[m], bfr[0], acc[m][0], 0, 0, 0);
            acc[m][1] = __builtin_amdgcn_mfma_f32_16x16x32_bf16(af[m], bfr[1], acc[m][1], 0, 0, 0);
        }
        __builtin_amdgcn_s_setprio(0);
        __builtin_amdgcn_s_barrier();

        // ---- phase 1: load B n2-3, compute quadrant (m0-3, n2-3)
        if (st) STAGE(t2, 1);
        bfr[2] = *(const bf16x8*)(Ab + boffs[2]);
        bfr[3] = *(const bf16x8*)(Ab + boffs[3]);
        __builtin_amdgcn_s_barrier();
        __builtin_amdgcn_s_setprio(1);
#pragma unroll
        for (int m = 0; m < 4; ++m) {
            acc[m][2] = __builtin_amdgcn_mfma_f32_16x16x32_bf16(af[m], bfr[2], acc[m][2], 0, 0, 0);
            acc[m][3] = __builtin_amdgcn_mfma_f32_16x16x32_bf16(af[m], bfr[3], acc[m][3], 0, 0, 0);
        }
        __builtin_amdgcn_s_setprio(0);
        __builtin_amdgcn_s_barrier();

        // ---- phase 2: load A m4-7, compute quadrant (m4-7, n2-3)
        if (st) STAGE(t2, 2);
#pragma unroll
        for (int m = 0; m < 4; ++m) af[m] = *(const bf16x8*)(Ab + aoffs[4 + m]);
        __builtin_amdgcn_s_barrier();
        __builtin_amdgcn_s_setprio(1);
#pragma unroll
        for (int m = 0; m < 4; ++m) {
            acc[4 + m][2] = __builtin_amdgcn_mfma_f32_16x16x32_bf16(af[m], bfr[2], acc[4 + m][2], 0, 0, 0);
            acc[4 + m][3] = __builtin_amdgcn_mfma_f32_16x16x32_bf16(af[m], bfr[3], acc[4 + m][3], 0, 0, 0);
        }
        __builtin_amdgcn_s_setprio(0);
        __builtin_amdgcn_s_barrier();

        // ---- phase 3: no loads, compute quadrant (m4-7, n0-1)
        if (st) STAGE(t2, 3);
        __builtin_amdgcn_s_barrier();
        __builtin_amdgcn_s_setprio(1);
#pragma unroll
        for (int m = 0; m < 4; ++m) {
            acc[4 + m][0] = __builtin_amdgcn_mfma_f32_16x16x32_bf16(af[m], bfr[0], acc[4 + m][0], 0, 0, 0);
            acc[4 + m][1] = __builtin_amdgcn_mfma_f32_16x16x32_bf16(af[m], bfr[1], acc[4 + m][1], 0, 0, 0);
        }
        __builtin_amdgcn_s_setprio(0);
        __builtin_amdgcn_s_barrier();
    }
#undef STAGE

    // ---- epilogue: dist + masks + row-side reductions ----
    float sqj[4];
    int taj[4], tbj[4];
#pragma unroll
    for (int n = 0; n < 4; ++n) {
        int j = bj * BT + wn * 64 + n * 16 + l15;
        sqj[n] = sqv[j];
        taj[n] = ta[j];
        tbj[n] = tb[j];
    }
    const float INF = __uint_as_float(0x7F800000u);
#pragma unroll
    for (int m = 0; m < 8; ++m) {
#pragma unroll
        for (int reg = 0; reg < 4; ++reg) {
            const int i = bi * BT + wm * 128 + m * 16 + (lane >> 4) * 4 + reg;
            const float sqi = sqv[i];
            const int tai = ta[i], tbi = tb[i];
            float vhp = 0.f, vhn = INF, vmor = 0.f, vmir = INF, vany = 0.f;
#pragma unroll
            for (int n = 0; n < 4; ++n) {
                float d2 = sqi + sqj[n] - 2.f * acc[m][n][reg];
                float d = sqrtf(fmaxf(d2, 1e-12f));
                bool ma = (tai == taj[n]), mb = (tbi == tbj[n]);
                if (ma && mb) {
                    vhp = fmaxf(vhp, d);
                } else if (ma != mb) {
                    vmor = fmaxf(vmor, d);
                    vmir = fminf(vmir, d);
                    vany = 1.f;
                } else {
                    vhn = fminf(vhn, d);
                }
            }
#pragma unroll
            for (int s = 1; s < 16; s <<= 1) {
                vhp = fmaxf(vhp, __shfl_xor(vhp, s, 16));
                vhn = fminf(vhn, __shfl_xor(vhn, s, 16));
                vmor = fmaxf(vmor, __shfl_xor(vmor, s, 16));
                vmir = fminf(vmir, __shfl_xor(vmir, s, 16));
                vany = fmaxf(vany, __shfl_xor(vany, s, 16));
            }
            if (l15 == 0) {
                if (vhp > 0.f) atomicMax(&hp[i], __float_as_uint(vhp));
                if (vhn < INF) atomicMin(&hn[i], __float_as_uint(vhn));
                if (vany > 0.f) {
                    atomicMax(&mor[i], __float_as_uint(vmor));
                    atomicMin(&mir[i], __float_as_uint(vmir));
                    atomicOr(&anyor[i], 1);
                }
            }
        }
    }
}

// Kernel 4: final scalar loss (16 blocks, one row per thread, atomicAdd).
__global__ __launch_bounds__(256) void k_final(const unsigned* __restrict__ hp,
                                               const unsigned* __restrict__ hn,
                                               const unsigned* __restrict__ mor,
                                               const unsigned* __restrict__ mir,
                                               const int* __restrict__ anyor,
                                               const int* __restrict__ epoch_p,
                                               float* __restrict__ out) {
    const int t = threadIdx.x;
    const int i = blockIdx.x * 256 + t;
    const bool eok = (*epoch_p > 50);
    float fhp = __uint_as_float(hp[i]);
    float fhn = __uint_as_float(hn[i]);
    bool use_or = (anyor[i] != 0) && eok;
    float sp = use_or ? __uint_as_float(mor[i]) : fhp;
    float sn = use_or ? __uint_as_float(mir[i]) : fhn;
    float s = fmaxf(0.f, fhp - fhn + 0.3f) + fmaxf(0.f, sp - fhn + 0.3f) +
              fmaxf(0.f, fhp - sn + 0.3f);
#pragma unroll
    for (int sh = 32; sh > 0; sh >>= 1) s += __shfl_xor(s, sh);
    __shared__ float red[4];
    const int lane = t & 63, wid = t >> 6;
    if (lane == 0) red[wid] = s;
    __syncthreads();
    if (t == 0)
        atomicAdd(out, (red[0] + red[1] + red[2] + red[3]) * (1.f / 4096.f));
}

extern "C" void kernel_launch(void* const* d_in, const int* in_sizes, int n_in,
                              void* d_out, int out_size, void* d_ws, size_t ws_size,
                              hipStream_t stream) {
    const float* X = (const float*)d_in[0];
    const int* ta = (const int*)d_in[1];
    const int* tb = (const int*)d_in[2];
    const int* epoch_p = (const int*)d_in[4];
    float* out = (float*)d_out;

    char* ws = (char*)d_ws;
    unsigned short* Xb = (unsigned short*)ws;  // 16 MB bf16 copy
    size_t off = (size_t)NROW * KDIM * sizeof(unsigned short);
    float* sqv = (float*)(ws + off); off += (size_t)NROW * 4;
    unsigned* hp = (unsigned*)(ws + off); off += (size_t)NROW * 4;
    unsigned* hn = (unsigned*)(ws + off); off += (size_t)NROW * 4;
    unsigned* mor = (unsigned*)(ws + off); off += (size_t)NROW * 4;
    unsigned* mir = (unsigned*)(ws + off); off += (size_t)NROW * 4;
    int* anyor = (int*)(ws + off); off += (size_t)NROW * 4;

    k_convert<<<NROW, 256, 0, stream>>>(X, Xb, sqv);
    k_init<<<NROW / 256, 256, 0, stream>>>(hp, hn, mor, mir, anyor, out);
    k_gemm<<<(NROW / BT) * (NROW / BT), 512, 0, stream>>>(Xb, sqv, ta, tb,
                                                          hp, hn, mor, mir, anyor);
    k_final<<<NROW / 256, 256, 0, stream>>>(hp, hn, mor, mir, anyor, epoch_p, out);
}

// Round 4
// 109.631 us; speedup vs baseline: 1.4360x; 1.0277x over previous
//
#include <hip/hip_runtime.h>
#include <hip/hip_bf16.h>

#define NROW 4096
#define KDIM 2048
#define ROWB (KDIM * 2)     // bytes per Xb row
#define BT 256              // block tile (M = N)
#define BK 64               // k-tile depth (128 bytes)
#define NT (KDIM / BK)      // 32 k-tiles
#define LDSBUF 65536        // per k-tile: A 32 KB + B 32 KB
#define PHI(r) (((r) & 7) << 4)

typedef __attribute__((ext_vector_type(8))) short bf16x8;
typedef __attribute__((ext_vector_type(4))) float f32x4;
typedef __attribute__((ext_vector_type(4))) unsigned short u16x4;

__device__ __forceinline__ unsigned short f2bf(float x) {
    unsigned u = __float_as_uint(x);
    unsigned r = (u + 0x7FFFu + ((u >> 16) & 1u)) >> 16;
    return (unsigned short)r;
}
__device__ __forceinline__ float bf2f(unsigned short b) {
    return __uint_as_float(((unsigned)b) << 16);
}

// Kernel 1: fp32 -> bf16 copy + row sum-of-squares from the bf16 values.
__global__ __launch_bounds__(256) void k_convert(const float* __restrict__ X,
                                                 unsigned short* __restrict__ Xb,
                                                 float* __restrict__ sqv) {
    const int row = blockIdx.x;
    const int t = threadIdx.x;
    const float4* xr = (const float4*)(X + (size_t)row * KDIM);
    unsigned short* br = Xb + (size_t)row * KDIM;
    float acc = 0.f;
#pragma unroll
    for (int it = 0; it < 2; ++it) {
        int idx = t * 2 + it;
        float4 v = xr[idx];
        u16x4 b;
        b.x = f2bf(v.x); b.y = f2bf(v.y); b.z = f2bf(v.z); b.w = f2bf(v.w);
        float f0 = bf2f(b.x), f1 = bf2f(b.y), f2 = bf2f(b.z), f3 = bf2f(b.w);
        acc += f0 * f0 + f1 * f1 + f2 * f2 + f3 * f3;
        *(u16x4*)(br + idx * 4) = b;
    }
#pragma unroll
    for (int s = 32; s > 0; s >>= 1) acc += __shfl_xor(acc, s);
    __shared__ float red[4];
    const int lane = t & 63, wid = t >> 6;
    if (lane == 0) red[wid] = acc;
    __syncthreads();
    if (t == 0) sqv[row] = red[0] + red[1] + red[2] + red[3];
}

// Kernel 2: init per-row accumulators + zero the output scalar.
__global__ __launch_bounds__(256) void k_init(unsigned* hp, unsigned* hn,
                                              unsigned* mor, unsigned* mir,
                                              int* anyor, float* out) {
    int i = blockIdx.x * 256 + threadIdx.x;
    hp[i] = 0u;
    hn[i] = 0x7F800000u;
    mor[i] = 0u;
    mir[i] = 0x7F800000u;
    anyor[i] = 0;
    if (i == 0) out[0] = 0.f;
}

// Kernel 3: 256x256 Gram GEMM, BK=64, 8 waves, double-buffered LDS (128 KiB),
// 4 phases x 16 MFMA per K-tile, counted vmcnt (never drains mid-loop),
// setprio around MFMA clusters, source-side XOR swizzle (PHI = (r&7)<<4).
// Chunk order [0,2,4,5 | 6,7,1,3]: tile-top needs all but A-chunks {1,3}
// (-> vmcnt(2)); phase 2 needs {1,3} (-> vmcnt(8) at ph1 tail, leaving the
// next tile's 8 loads in flight).
__global__ __launch_bounds__(512, 2) void k_gemm(const unsigned short* __restrict__ Xb,
                                                 const float* __restrict__ sqv,
                                                 const int* __restrict__ ta,
                                                 const int* __restrict__ tb,
                                                 unsigned int* __restrict__ hp,
                                                 unsigned int* __restrict__ hn,
                                                 unsigned int* __restrict__ mor,
                                                 unsigned int* __restrict__ mir,
                                                 int* __restrict__ anyor) {
    __shared__ char lds[2 * LDSBUF];  // 128 KiB
    const int bi = blockIdx.x >> 4;
    const int bj = blockIdx.x & 15;
    const int t = threadIdx.x;
    const int lane = t & 63;
    const int w = t >> 6;        // wave 0..7
    const int wm = w >> 2;       // 0..1  (128-row half of A)
    const int wn = w & 3;        // 0..3  (64-col quarter of B)
    const int l15 = lane & 15;
    const int kg16 = (lane >> 4) * 16;  // k-group byte offset within 32-k slot
    const char* xbase = (const char*)Xb;

    // swizzled ds_read byte offsets within a buffer
    int aoff[8][2], boff[4][2];
#pragma unroll
    for (int m = 0; m < 8; ++m) {
        const int r = wm * 128 + m * 16 + l15;
#pragma unroll
        for (int ks = 0; ks < 2; ++ks)
            aoff[m][ks] = r * 128 + ((ks * 64 + kg16) ^ PHI(r));
    }
#pragma unroll
    for (int n = 0; n < 4; ++n) {
        const int j = wn * 64 + n * 16 + l15;
#pragma unroll
        for (int ks = 0; ks < 2; ++ks)
            boff[n][ks] = 32768 + j * 128 + ((ks * 64 + kg16) ^ PHI(j));
    }

    f32x4 acc[8][4] = {};

    // stage 8 KB chunk p of k-tile tt into buf tt&1. Chunk p<4: A rows
    // p*64..p*64+63; p>=4: B rows (p-4)*64... Thread t covers row t>>3 of the
    // chunk, 16B column (t&7). LDS dest linear; swizzle on the global source.
#define STAGE(tt, p)                                                          \
    do {                                                                      \
        constexpr int isb_ = (p) >= 4;                                        \
        constexpr int c_ = (p) - isb_ * 4;                                    \
        const int row_ = c_ * 64 + (t >> 3);                                  \
        const int gr_ = (isb_ ? bj : bi) * BT + row_;                         \
        const char* gsrc_ = xbase + (size_t)gr_ * ROWB + (size_t)(tt) * 128 + \
                            (((t & 7) * 16) ^ PHI(row_));                     \
        char* ldst_ = lds + ((tt) & 1) * LDSBUF + isb_ * 32768 + row_ * 128 + \
                      (t & 7) * 16;                                           \
        __builtin_amdgcn_global_load_lds(                                     \
            (const __attribute__((address_space(1))) void*)gsrc_,             \
            (__attribute__((address_space(3))) void*)ldst_, 16, 0, 0);        \
    } while (0)

    // prologue: stage tile 0 in need-order, wait all but chunks {1,3}
    STAGE(0, 0); STAGE(0, 2); STAGE(0, 4); STAGE(0, 5);
    STAGE(0, 6); STAGE(0, 7); STAGE(0, 1); STAGE(0, 3);
    asm volatile("s_waitcnt vmcnt(2)" ::: "memory");
    __builtin_amdgcn_s_barrier();

    bf16x8 af[4][2], bfr[4][2];
    for (int tk = 0; tk < NT; ++tk) {
        const char* bufb = lds + (tk & 1) * LDSBUF;
        const bool stg = (tk + 1) < NT;

        // ---- phase 0: stage next {0,2,4,5}; read A m0-3 + B n0-1; MFMA q00
        if (stg) { STAGE(tk + 1, 0); STAGE(tk + 1, 2); STAGE(tk + 1, 4); STAGE(tk + 1, 5); }
#pragma unroll
        for (int m = 0; m < 4; ++m) {
            af[m][0] = *(const bf16x8*)(bufb + aoff[m][0]);
            af[m][1] = *(const bf16x8*)(bufb + aoff[m][1]);
        }
#pragma unroll
        for (int n = 0; n < 2; ++n) {
            bfr[n][0] = *(const bf16x8*)(bufb + boff[n][0]);
            bfr[n][1] = *(const bf16x8*)(bufb + boff[n][1]);
        }
        __builtin_amdgcn_s_barrier();
        __builtin_amdgcn_s_setprio(1);
#pragma unroll
        for (int ks = 0; ks < 2; ++ks)
#pragma unroll
            for (int m = 0; m < 4; ++m) {
                acc[m][0] = __builtin_amdgcn_mfma_f32_16x16x32_bf16(af[m][ks], bfr[0][ks], acc[m][0], 0, 0, 0);
                acc[m][1] = __builtin_amdgcn_mfma_f32_16x16x32_bf16(af[m][ks], bfr[1][ks], acc[m][1], 0, 0, 0);
            }
        __builtin_amdgcn_s_setprio(0);
        __builtin_amdgcn_s_barrier();

        // ---- phase 1: stage next {6,7,1,3}; read B n2-3; MFMA q01
        if (stg) { STAGE(tk + 1, 6); STAGE(tk + 1, 7); STAGE(tk + 1, 1); STAGE(tk + 1, 3); }
#pragma unroll
        for (int n = 2; n < 4; ++n) {
            bfr[n][0] = *(const bf16x8*)(bufb + boff[n][0]);
            bfr[n][1] = *(const bf16x8*)(bufb + boff[n][1]);
        }
        __builtin_amdgcn_s_barrier();
        __builtin_amdgcn_s_setprio(1);
#pragma unroll
        for (int ks = 0; ks < 2; ++ks)
#pragma unroll
            for (int m = 0; m < 4; ++m) {
                acc[m][2] = __builtin_amdgcn_mfma_f32_16x16x32_bf16(af[m][ks], bfr[2][ks], acc[m][2], 0, 0, 0);
                acc[m][3] = __builtin_amdgcn_mfma_f32_16x16x32_bf16(af[m][ks], bfr[3][ks], acc[m][3], 0, 0, 0);
            }
        __builtin_amdgcn_s_setprio(0);
        // this tile's A-chunks {1,3} must be resident for phase 2
        if (stg)
            asm volatile("s_waitcnt vmcnt(8)" ::: "memory");
        else
            asm volatile("s_waitcnt vmcnt(0)" ::: "memory");
        __builtin_amdgcn_s_barrier();

        // ---- phase 2: read A m4-7; MFMA q12
#pragma unroll
        for (int m = 0; m < 4; ++m) {
            af[m][0] = *(const bf16x8*)(bufb + aoff[4 + m][0]);
            af[m][1] = *(const bf16x8*)(bufb + aoff[4 + m][1]);
        }
        __builtin_amdgcn_s_barrier();
        __builtin_amdgcn_s_setprio(1);
#pragma unroll
        for (int ks = 0; ks < 2; ++ks)
#pragma unroll
            for (int m = 0; m < 4; ++m) {
                acc[4 + m][2] = __builtin_amdgcn_mfma_f32_16x16x32_bf16(af[m][ks], bfr[2][ks], acc[4 + m][2], 0, 0, 0);
                acc[4 + m][3] = __builtin_amdgcn_mfma_f32_16x16x32_bf16(af[m][ks], bfr[3][ks], acc[4 + m][3], 0, 0, 0);
            }
        __builtin_amdgcn_s_setprio(0);
        __builtin_amdgcn_s_barrier();

        // ---- phase 3: no reads; MFMA q10; tail = next-tile-top wait
        __builtin_amdgcn_s_setprio(1);
#pragma unroll
        for (int ks = 0; ks < 2; ++ks)
#pragma unroll
            for (int m = 0; m < 4; ++m) {
                acc[4 + m][0] = __builtin_amdgcn_mfma_f32_16x16x32_bf16(af[m][ks], bfr[0][ks], acc[4 + m][0], 0, 0, 0);
                acc[4 + m][1] = __builtin_amdgcn_mfma_f32_16x16x32_bf16(af[m][ks], bfr[1][ks], acc[4 + m][1], 0, 0, 0);
            }
        __builtin_amdgcn_s_setprio(0);
        // next tile needs chunks {0,2,4,5,6,7}; leave its {1,3} in flight
        if (stg) asm volatile("s_waitcnt vmcnt(2)" ::: "memory");
        __builtin_amdgcn_s_barrier();
    }
#undef STAGE

    // ---- epilogue: dist + masks + row-side reductions ----
    float sqj[4];
    int taj[4], tbj[4];
#pragma unroll
    for (int n = 0; n < 4; ++n) {
        int j = bj * BT + wn * 64 + n * 16 + l15;
        sqj[n] = sqv[j];
        taj[n] = ta[j];
        tbj[n] = tb[j];
    }
    const float INF = __uint_as_float(0x7F800000u);
#pragma unroll
    for (int m = 0; m < 8; ++m) {
#pragma unroll
        for (int reg = 0; reg < 4; ++reg) {
            const int i = bi * BT + wm * 128 + m * 16 + (lane >> 4) * 4 + reg;
            const float sqi = sqv[i];
            const int tai = ta[i], tbi = tb[i];
            float vhp = 0.f, vhn = INF, vmor = 0.f, vmir = INF, vany = 0.f;
#pragma unroll
            for (int n = 0; n < 4; ++n) {
                float d2 = sqi + sqj[n] - 2.f * acc[m][n][reg];
                float d = sqrtf(fmaxf(d2, 1e-12f));
                bool ma = (tai == taj[n]), mb = (tbi == tbj[n]);
                if (ma && mb) {
                    vhp = fmaxf(vhp, d);
                } else if (ma != mb) {
                    vmor = fmaxf(vmor, d);
                    vmir = fminf(vmir, d);
                    vany = 1.f;
                } else {
                    vhn = fminf(vhn, d);
                }
            }
#pragma unroll
            for (int s = 1; s < 16; s <<= 1) {
                vhp = fmaxf(vhp, __shfl_xor(vhp, s, 16));
                vhn = fminf(vhn, __shfl_xor(vhn, s, 16));
                vmor = fmaxf(vmor, __shfl_xor(vmor, s, 16));
                vmir = fminf(vmir, __shfl_xor(vmir, s, 16));
                vany = fmaxf(vany, __shfl_xor(vany, s, 16));
            }
            if (l15 == 0) {
                if (vhp > 0.f) atomicMax(&hp[i], __float_as_uint(vhp));
                if (vhn < INF) atomicMin(&hn[i], __float_as_uint(vhn));
                if (vany > 0.f) {
                    atomicMax(&mor[i], __float_as_uint(vmor));
                    atomicMin(&mir[i], __float_as_uint(vmir));
                    atomicOr(&anyor[i], 1);
                }
            }
        }
    }
}

// Kernel 4: final scalar loss (16 blocks, one row per thread, atomicAdd).
__global__ __launch_bounds__(256) void k_final(const unsigned* __restrict__ hp,
                                               const unsigned* __restrict__ hn,
                                               const unsigned* __restrict__ mor,
                                               const unsigned* __restrict__ mir,
                                               const int* __restrict__ anyor,
                                               const int* __restrict__ epoch_p,
                                               float* __restrict__ out) {
    const int t = threadIdx.x;
    const int i = blockIdx.x * 256 + t;
    const bool eok = (*epoch_p > 50);
    float fhp = __uint_as_float(hp[i]);
    float fhn = __uint_as_float(hn[i]);
    bool use_or = (anyor[i] != 0) && eok;
    float sp = use_or ? __uint_as_float(mor[i]) : fhp;
    float sn = use_or ? __uint_as_float(mir[i]) : fhn;
    float s = fmaxf(0.f, fhp - fhn + 0.3f) + fmaxf(0.f, sp - fhn + 0.3f) +
              fmaxf(0.f, fhp - sn + 0.3f);
#pragma unroll
    for (int sh = 32; sh > 0; sh >>= 1) s += __shfl_xor(s, sh);
    __shared__ float red[4];
    const int lane = t & 63, wid = t >> 6;
    if (lane == 0) red[wid] = s;
    __syncthreads();
    if (t == 0)
        atomicAdd(out, (red[0] + red[1] + red[2] + red[3]) * (1.f / 4096.f));
}

extern "C" void kernel_launch(void* const* d_in, const int* in_sizes, int n_in,
                              void* d_out, int out_size, void* d_ws, size_t ws_size,
                              hipStream_t stream) {
    const float* X = (const float*)d_in[0];
    const int* ta = (const int*)d_in[1];
    const int* tb = (const int*)d_in[2];
    const int* epoch_p = (const int*)d_in[4];
    float* out = (float*)d_out;

    char* ws = (char*)d_ws;
    unsigned short* Xb = (unsigned short*)ws;  // 16 MB bf16 copy
    size_t off = (size_t)NROW * KDIM * sizeof(unsigned short);
    float* sqv = (float*)(ws + off); off += (size_t)NROW * 4;
    unsigned* hp = (unsigned*)(ws + off); off += (size_t)NROW * 4;
    unsigned* hn = (unsigned*)(ws + off); off += (size_t)NROW * 4;
    unsigned* mor = (unsigned*)(ws + off); off += (size_t)NROW * 4;
    unsigned* mir = (unsigned*)(ws + off); off += (size_t)NROW * 4;
    int* anyor = (int*)(ws + off); off += (size_t)NROW * 4;

    k_convert<<<NROW, 256, 0, stream>>>(X, Xb, sqv);
    k_init<<<NROW / 256, 256, 0, stream>>>(hp, hn, mor, mir, anyor, out);
    k_gemm<<<(NROW / BT) * (NROW / BT), 512, 0, stream>>>(Xb, sqv, ta, tb,
                                                          hp, hn, mor, mir, anyor);
    k_final<<<NROW / 256, 256, 0, stream>>>(hp, hn, mor, mir, anyor, epoch_p, out);
}

// Round 5
// 108.218 us; speedup vs baseline: 1.4547x; 1.0131x over previous
//
#include <hip/hip_runtime.h>
#include <hip/hip_bf16.h>

#define NROW 4096
#define KDIM 2048
#define ROWB (KDIM * 2)     // bytes per Xb row
#define BT 256              // block tile (M = N)
#define BK 64               // k-tile depth (128 bytes)
#define NT (KDIM / BK)      // 32 k-tiles
#define LDSBUF 65536        // per k-tile: A 32 KB + B 32 KB
#define PHI(r) (((r) & 7) << 4)

typedef __attribute__((ext_vector_type(8))) short bf16x8;
typedef __attribute__((ext_vector_type(4))) float f32x4;
typedef __attribute__((ext_vector_type(4))) unsigned short u16x4;

#define MFMA16(a, b, c) __builtin_amdgcn_mfma_f32_16x16x32_bf16((a), (b), (c), 0, 0, 0)

__device__ __forceinline__ unsigned short f2bf(float x) {
    unsigned u = __float_as_uint(x);
    unsigned r = (u + 0x7FFFu + ((u >> 16) & 1u)) >> 16;
    return (unsigned short)r;
}
__device__ __forceinline__ float bf2f(unsigned short b) {
    return __uint_as_float(((unsigned)b) << 16);
}

// Kernel 1: fp32 -> bf16 copy + row sum-of-squares from the bf16 values.
__global__ __launch_bounds__(256) void k_convert(const float* __restrict__ X,
                                                 unsigned short* __restrict__ Xb,
                                                 float* __restrict__ sqv) {
    const int row = blockIdx.x;
    const int t = threadIdx.x;
    const float4* xr = (const float4*)(X + (size_t)row * KDIM);
    unsigned short* br = Xb + (size_t)row * KDIM;
    float acc = 0.f;
#pragma unroll
    for (int it = 0; it < 2; ++it) {
        int idx = t * 2 + it;
        float4 v = xr[idx];
        u16x4 b;
        b.x = f2bf(v.x); b.y = f2bf(v.y); b.z = f2bf(v.z); b.w = f2bf(v.w);
        float f0 = bf2f(b.x), f1 = bf2f(b.y), f2 = bf2f(b.z), f3 = bf2f(b.w);
        acc += f0 * f0 + f1 * f1 + f2 * f2 + f3 * f3;
        *(u16x4*)(br + idx * 4) = b;
    }
#pragma unroll
    for (int s = 32; s > 0; s >>= 1) acc += __shfl_xor(acc, s);
    __shared__ float red[4];
    const int lane = t & 63, wid = t >> 6;
    if (lane == 0) red[wid] = acc;
    __syncthreads();
    if (t == 0) sqv[row] = red[0] + red[1] + red[2] + red[3];
}

// Kernel 2: init per-row accumulators + zero the output scalar.
__global__ __launch_bounds__(256) void k_init(unsigned* hp, unsigned* hn,
                                              unsigned* mor, unsigned* mir,
                                              int* anyor, float* out) {
    int i = blockIdx.x * 256 + threadIdx.x;
    hp[i] = 0u;
    hn[i] = 0x7F800000u;
    mor[i] = 0u;
    mir[i] = 0x7F800000u;
    anyor[i] = 0;
    if (i == 0) out[0] = 0.f;
}

// Kernel 3: 256x256 Gram GEMM, BK=64, 8 waves, double-buffered LDS.
// Software-pipelined fragment reads: every ds_read is issued one phase
// before its MFMA uses it, so the LDS pipe drains under the MFMA window
// (lgkm waits land a phase late, compiler-counted). Counted vmcnt only
// (8/2, drain only at the last tile). Source-side XOR swizzle (rule #21).
__global__ __launch_bounds__(512, 2) void k_gemm(const unsigned short* __restrict__ Xb,
                                                 const float* __restrict__ sqv,
                                                 const int* __restrict__ ta,
                                                 const int* __restrict__ tb,
                                                 unsigned int* __restrict__ hp,
                                                 unsigned int* __restrict__ hn,
                                                 unsigned int* __restrict__ mor,
                                                 unsigned int* __restrict__ mir,
                                                 int* __restrict__ anyor) {
    __shared__ char lds[2 * LDSBUF];  // 128 KiB
    const int bi = blockIdx.x >> 4;
    const int bj = blockIdx.x & 15;
    const int t = threadIdx.x;
    const int lane = t & 63;
    const int w = t >> 6;        // wave 0..7
    const int wm = w >> 2;       // 0..1  (128-row half of A)
    const int wn = w & 3;        // 0..3  (64-col quarter of B)
    const int l15 = lane & 15;
    const int kg16 = (lane >> 4) * 16;  // k-group byte offset within 64B k-slot
    const char* xbase = (const char*)Xb;

    // ds_read bases: swizzle XOR P=(l15&7)<<4 is lane-constant; row offsets
    // become compile-time +m*2048 immediates (saves ~20 VGPRs vs offset arrays)
    const int P = (l15 & 7) << 4;
    int akb[2], bkb[2];
#pragma unroll
    for (int ks = 0; ks < 2; ++ks) {
        const int kx = (ks * 64 + kg16) ^ P;  // disjoint bits -> bitwise xor ok
        akb[ks] = (wm * 128 + l15) * 128 + kx;
        bkb[ks] = 32768 + (wn * 64 + l15) * 128 + kx;
    }

    f32x4 acc[8][4] = {};

    // stage 8 KB chunk p of k-tile tt into buf tt&1. Chunk p<4: A rows
    // p*64+63; p>=4: B rows (p-4)*64... thread t covers row t>>3, 16B col t&7.
#define STAGE(tt, p)                                                          \
    do {                                                                      \
        constexpr int isb_ = (p) >= 4;                                        \
        constexpr int c_ = (p) - isb_ * 4;                                    \
        const int row_ = c_ * 64 + (t >> 3);                                  \
        const int gr_ = (isb_ ? bj : bi) * BT + row_;                         \
        const char* gsrc_ = xbase + (size_t)gr_ * ROWB + (size_t)(tt) * 128 + \
                            (((t & 7) * 16) ^ PHI(row_));                     \
        char* ldst_ = lds + ((tt) & 1) * LDSBUF + isb_ * 32768 + row_ * 128 + \
                      (t & 7) * 16;                                           \
        __builtin_amdgcn_global_load_lds(                                     \
            (const __attribute__((address_space(1))) void*)gsrc_,             \
            (__attribute__((address_space(3))) void*)ldst_, 16, 0, 0);        \
    } while (0)

    // prologue: stage tile 0 (chunks {1,3} last), wait all but {1,3},
    // pre-read A0(0)+B01(0) so P0's MFMA has operands.
    STAGE(0, 0); STAGE(0, 2); STAGE(0, 4); STAGE(0, 5);
    STAGE(0, 6); STAGE(0, 7); STAGE(0, 1); STAGE(0, 3);
    asm volatile("s_waitcnt vmcnt(2)" ::: "memory");
    __builtin_amdgcn_s_barrier();

    bf16x8 af0[4][2], af1[4][2], b01[2][2], b23[2][2];
#pragma unroll
    for (int ks = 0; ks < 2; ++ks) {
#pragma unroll
        for (int m = 0; m < 4; ++m)
            af0[m][ks] = *(const bf16x8*)(lds + akb[ks] + m * 2048);
        b01[0][ks] = *(const bf16x8*)(lds + bkb[ks]);
        b01[1][ks] = *(const bf16x8*)(lds + bkb[ks] + 2048);
    }

    for (int tk = 0; tk < NT; ++tk) {
        const char* bufc = lds + (tk & 1) * LDSBUF;
        const char* bufn = lds + ((tk + 1) & 1) * LDSBUF;
        const bool stg = (tk + 1) < NT;

        // ---- P0: stage 6 chunks(next); read B23(cur) [for P1]; MFMA q00
        if (stg) {
            STAGE(tk + 1, 0); STAGE(tk + 1, 2); STAGE(tk + 1, 4);
            STAGE(tk + 1, 5); STAGE(tk + 1, 6); STAGE(tk + 1, 7);
        }
#pragma unroll
        for (int ks = 0; ks < 2; ++ks) {
            b23[0][ks] = *(const bf16x8*)(bufc + bkb[ks] + 2 * 2048);
            b23[1][ks] = *(const bf16x8*)(bufc + bkb[ks] + 3 * 2048);
        }
        __builtin_amdgcn_s_setprio(1);
#pragma unroll
        for (int ks = 0; ks < 2; ++ks)
#pragma unroll
            for (int m = 0; m < 4; ++m) {
                acc[m][0] = MFMA16(af0[m][ks], b01[0][ks], acc[m][0]);
                acc[m][1] = MFMA16(af0[m][ks], b01[1][ks], acc[m][1]);
            }
        __builtin_amdgcn_s_setprio(0);

        // ---- P1: stage {1,3}(next); vmcnt+bar; read A1(cur) [for P2]; q01
        if (stg) {
            STAGE(tk + 1, 1); STAGE(tk + 1, 3);
            asm volatile("s_waitcnt vmcnt(8)" ::: "memory");  // {1,3}(cur) in
        } else {
            asm volatile("s_waitcnt vmcnt(0)" ::: "memory");
        }
        __builtin_amdgcn_s_barrier();
#pragma unroll
        for (int ks = 0; ks < 2; ++ks)
#pragma unroll
            for (int m = 0; m < 4; ++m)
                af1[m][ks] = *(const bf16x8*)(bufc + akb[ks] + (4 + m) * 2048);
        __builtin_amdgcn_s_setprio(1);
#pragma unroll
        for (int ks = 0; ks < 2; ++ks)
#pragma unroll
            for (int m = 0; m < 4; ++m) {
                acc[m][2] = MFMA16(af0[m][ks], b23[0][ks], acc[m][2]);
                acc[m][3] = MFMA16(af0[m][ks], b23[1][ks], acc[m][3]);
            }
        __builtin_amdgcn_s_setprio(0);

        // ---- P2: vmcnt(2)+bar; read A0(next) [for P0']; MFMA q12
        if (stg) {
            asm volatile("s_waitcnt vmcnt(2)" ::: "memory");  // 6 chunks(next) in
            __builtin_amdgcn_s_barrier();
#pragma unroll
            for (int ks = 0; ks < 2; ++ks)
#pragma unroll
                for (int m = 0; m < 4; ++m)
                    af0[m][ks] = *(const bf16x8*)(bufn + akb[ks] + m * 2048);
        }
        __builtin_amdgcn_s_setprio(1);
#pragma unroll
        for (int ks = 0; ks < 2; ++ks)
#pragma unroll
            for (int m = 0; m < 4; ++m) {
                acc[4 + m][2] = MFMA16(af1[m][ks], b23[0][ks], acc[4 + m][2]);
                acc[4 + m][3] = MFMA16(af1[m][ks], b23[1][ks], acc[4 + m][3]);
            }
        __builtin_amdgcn_s_setprio(0);

        // ---- P3: MFMA q10; then read B01(next) [for P0']; bar
        __builtin_amdgcn_s_setprio(1);
#pragma unroll
        for (int ks = 0; ks < 2; ++ks)
#pragma unroll
            for (int m = 0; m < 4; ++m) {
                acc[4 + m][0] = MFMA16(af1[m][ks], b01[0][ks], acc[4 + m][0]);
                acc[4 + m][1] = MFMA16(af1[m][ks], b01[1][ks], acc[4 + m][1]);
            }
        __builtin_amdgcn_s_setprio(0);
        if (stg) {
#pragma unroll
            for (int ks = 0; ks < 2; ++ks) {
                b01[0][ks] = *(const bf16x8*)(bufn + bkb[ks]);
                b01[1][ks] = *(const bf16x8*)(bufn + bkb[ks] + 2048);
            }
        }
        __builtin_amdgcn_s_barrier();
    }
#undef STAGE

    // ---- epilogue: dist + masks + row-side reductions ----
    float sqj[4];
    int taj[4], tbj[4];
#pragma unroll
    for (int n = 0; n < 4; ++n) {
        int j = bj * BT + wn * 64 + n * 16 + l15;
        sqj[n] = sqv[j];
        taj[n] = ta[j];
        tbj[n] = tb[j];
    }
    const float INF = __uint_as_float(0x7F800000u);
#pragma unroll
    for (int m = 0; m < 8; ++m) {
#pragma unroll
        for (int reg = 0; reg < 4; ++reg) {
            const int i = bi * BT + wm * 128 + m * 16 + (lane >> 4) * 4 + reg;
            const float sqi = sqv[i];
            const int tai = ta[i], tbi = tb[i];
            float vhp = 0.f, vhn = INF, vmor = 0.f, vmir = INF, vany = 0.f;
#pragma unroll
            for (int n = 0; n < 4; ++n) {
                float d2 = sqi + sqj[n] - 2.f * acc[m][n][reg];
                float d = sqrtf(fmaxf(d2, 1e-12f));
                bool ma = (tai == taj[n]), mb = (tbi == tbj[n]);
                if (ma && mb) {
                    vhp = fmaxf(vhp, d);
                } else if (ma != mb) {
                    vmor = fmaxf(vmor, d);
                    vmir = fminf(vmir, d);
                    vany = 1.f;
                } else {
                    vhn = fminf(vhn, d);
                }
            }
#pragma unroll
            for (int s = 1; s < 16; s <<= 1) {
                vhp = fmaxf(vhp, __shfl_xor(vhp, s, 16));
                vhn = fminf(vhn, __shfl_xor(vhn, s, 16));
                vmor = fmaxf(vmor, __shfl_xor(vmor, s, 16));
                vmir = fminf(vmir, __shfl_xor(vmir, s, 16));
                vany = fmaxf(vany, __shfl_xor(vany, s, 16));
            }
            if (l15 == 0) {
                if (vhp > 0.f) atomicMax(&hp[i], __float_as_uint(vhp));
                if (vhn < INF) atomicMin(&hn[i], __float_as_uint(vhn));
                if (vany > 0.f) {
                    atomicMax(&mor[i], __float_as_uint(vmor));
                    atomicMin(&mir[i], __float_as_uint(vmir));
                    atomicOr(&anyor[i], 1);
                }
            }
        }
    }
}

// Kernel 4: final scalar loss (16 blocks, one row per thread, atomicAdd).
__global__ __launch_bounds__(256) void k_final(const unsigned* __restrict__ hp,
                                               const unsigned* __restrict__ hn,
                                               const unsigned* __restrict__ mor,
                                               const unsigned* __restrict__ mir,
                                               const int* __restrict__ anyor,
                                               const int* __restrict__ epoch_p,
                                               float* __restrict__ out) {
    const int t = threadIdx.x;
    const int i = blockIdx.x * 256 + t;
    const bool eok = (*epoch_p > 50);
    float fhp = __uint_as_float(hp[i]);
    float fhn = __uint_as_float(hn[i]);
    bool use_or = (anyor[i] != 0) && eok;
    float sp = use_or ? __uint_as_float(mor[i]) : fhp;
    float sn = use_or ? __uint_as_float(mir[i]) : fhn;
    float s = fmaxf(0.f, fhp - fhn + 0.3f) + fmaxf(0.f, sp - fhn + 0.3f) +
              fmaxf(0.f, fhp - sn + 0.3f);
#pragma unroll
    for (int sh = 32; sh > 0; sh >>= 1) s += __shfl_xor(s, sh);
    __shared__ float red[4];
    const int lane = t & 63, wid = t >> 6;
    if (lane == 0) red[wid] = s;
    __syncthreads();
    if (t == 0)
        atomicAdd(out, (red[0] + red[1] + red[2] + red[3]) * (1.f / 4096.f));
}

extern "C" void kernel_launch(void* const* d_in, const int* in_sizes, int n_in,
                              void* d_out, int out_size, void* d_ws, size_t ws_size,
                              hipStream_t stream) {
    const float* X = (const float*)d_in[0];
    const int* ta = (const int*)d_in[1];
    const int* tb = (const int*)d_in[2];
    const int* epoch_p = (const int*)d_in[4];
    float* out = (float*)d_out;

    char* ws = (char*)d_ws;
    unsigned short* Xb = (unsigned short*)ws;  // 16 MB bf16 copy
    size_t off = (size_t)NROW * KDIM * sizeof(unsigned short);
    float* sqv = (float*)(ws + off); off += (size_t)NROW * 4;
    unsigned* hp = (unsigned*)(ws + off); off += (size_t)NROW * 4;
    unsigned* hn = (unsigned*)(ws + off); off += (size_t)NROW * 4;
    unsigned* mor = (unsigned*)(ws + off); off += (size_t)NROW * 4;
    unsigned* mir = (unsigned*)(ws + off); off += (size_t)NROW * 4;
    int* anyor = (int*)(ws + off); off += (size_t)NROW * 4;

    k_convert<<<NROW, 256, 0, stream>>>(X, Xb, sqv);
    k_init<<<NROW / 256, 256, 0, stream>>>(hp, hn, mor, mir, anyor, out);
    k_gemm<<<(NROW / BT) * (NROW / BT), 512, 0, stream>>>(Xb, sqv, ta, tb,
                                                          hp, hn, mor, mir, anyor);
    k_final<<<NROW / 256, 256, 0, stream>>>(hp, hn, mor, mir, anyor, epoch_p, out);
}